// Round 1
// baseline (98.883 us; speedup 1.0000x reference)
//
#include <hip/hip_runtime.h>
#include <stdint.h>

#define SEQ   4096
#define KD    1024
#define MARG  60000.0f
#define BM    128
#define BK    64
#define NKT   (KD / BK)               // 16 K-steps
#define NTB   (SEQ / BM)              // 32 tile-rows
#define NBLK  (NTB * (NTB + 1) / 2)   // 528 lower-triangle blocks
// denom = 4096*4095*1000
#define DENOM 16773120000.0

typedef __attribute__((ext_vector_type(8))) __bf16 bf16x8;
typedef __attribute__((ext_vector_type(4))) float  f32x4;

__device__ __forceinline__ unsigned short f2bf(float f) {
  unsigned int b = __float_as_uint(f);
  b += 0x7FFFu + ((b >> 16) & 1u);   // RNE
  return (unsigned short)(b >> 16);
}

__device__ __forceinline__ void gload16(const void* g, void* l) {
  __builtin_amdgcn_global_load_lds(
      (const __attribute__((address_space(1))) void*)g,
      (__attribute__((address_space(3))) void*)l,
      16, 0, 0);
}

// ---------------- prep: Y[s][k]=bf16(x[n][s][f]), k=n*256+f ; s2[s]=sum x^2 ----------
__global__ __launch_bounds__(256) void prep_kernel(
    const float* __restrict__ x, unsigned short* __restrict__ Y,
    float* __restrict__ s2, double* __restrict__ acc) {
  const int s = blockIdx.x;
  const int t = threadIdx.x;
  if (s == 0 && t == 0) *acc = 0.0;      // zero loss accumulator (ws is poisoned each call)
  const int n  = t >> 6;                 // 0..3 (batch)
  const int f0 = (t & 63) << 2;          // 0..252 step 4
  const float4 v = *(const float4*)(x + (((size_t)(n * SEQ + s)) << 8) + f0);
  float sq = v.x * v.x + v.y * v.y + v.z * v.z + v.w * v.w;
  ushort4 u;
  u.x = f2bf(v.x); u.y = f2bf(v.y); u.z = f2bf(v.z); u.w = f2bf(v.w);
  *(ushort4*)(Y + (((size_t)s) << 10) + (n << 8) + f0) = u;
  #pragma unroll
  for (int o = 32; o; o >>= 1) sq += __shfl_down(sq, o, 64);
  __shared__ float wp[4];
  if ((t & 63) == 0) wp[t >> 6] = sq;
  __syncthreads();
  if (t == 0) s2[s] = wp[0] + wp[1] + wp[2] + wp[3];
}

// ---------------- gram tile + fused loss epilogue --------------------------------
// Lower-triangle block (bi>=bj). 256 thr = 4 waves, each wave a 64x64 sub-tile.
// LDS tiles [128][BK=64] bf16, 16B slots XOR-swizzled: slot' = slot ^ (row&7).
// global_load_lds writes linearly; swizzle applied on the GLOBAL source address,
// and the identical involution on the ds_read side.
__global__ __launch_bounds__(256) void gram_loss_kernel(
    const unsigned short* __restrict__ Y, const float* __restrict__ s2,
    double* __restrict__ acc_out) {
  __shared__ __align__(16) unsigned short As[BM * BK];
  __shared__ __align__(16) unsigned short Bs[BM * BK];

  // linear block id -> (bi, bj) with bi >= bj
  const int t = (int)blockIdx.x;
  int bi = (int)((sqrtf(8.0f * (float)t + 1.0f) - 1.0f) * 0.5f);
  while ((bi + 1) * (bi + 2) / 2 <= t) ++bi;
  while (bi * (bi + 1) / 2 > t) --bi;
  const int bj = t - bi * (bi + 1) / 2;
  const int a0 = bi * BM, b0 = bj * BM;

  const int tid  = threadIdx.x;
  const int lane = tid & 63;
  const int w    = tid >> 6;
  const int wm   = w >> 1, wn = w & 1;   // 2x2 wave grid, 64x64 each

  f32x4 acc[4][4] = {};

  const unsigned short* Ya = Y + ((size_t)a0 << 10);
  const unsigned short* Yb = Y + ((size_t)b0 << 10);

  for (int kt = 0; kt < NKT; ++kt) {
    __syncthreads();  // previous iteration's ds_reads done before overwrite
    #pragma unroll
    for (int r = 0; r < 4; ++r) {
      const int base = r * 4096 + w * 1024;       // wave-uniform LDS byte base
      const int off  = base + lane * 16;          // this lane's linear dest byte
      const int row  = off >> 7;                  // /128 bytes per row
      const int slot = (off >> 4) & 7;
      const int sl   = slot ^ (row & 7);          // pre-swizzled source slot
      const size_t goff = ((size_t)row << 10) + kt * BK + sl * 8;  // elements
      gload16(Ya + goff, (char*)As + base);
      gload16(Yb + goff, (char*)Bs + base);
    }
    __syncthreads();  // compiler drains vmcnt(0) before this barrier

    bf16x8 af[4][2], bfr[4][2];
    #pragma unroll
    for (int fm = 0; fm < 4; ++fm) {
      const int ra = wm * 64 + fm * 16 + (lane & 15);
      const int rb = wn * 64 + fm * 16 + (lane & 15);
      #pragma unroll
      for (int kk = 0; kk < 2; ++kk) {
        const int slot = kk * 4 + (lane >> 4);
        af[fm][kk]  = *(const bf16x8*)((const char*)As + ra * 128 + ((slot ^ (ra & 7)) << 4));
        bfr[fm][kk] = *(const bf16x8*)((const char*)Bs + rb * 128 + ((slot ^ (rb & 7)) << 4));
      }
    }
    #pragma unroll
    for (int kk = 0; kk < 2; ++kk)
      #pragma unroll
      for (int fm = 0; fm < 4; ++fm)
        #pragma unroll
        for (int fn = 0; fn < 4; ++fn)
          acc[fm][fn] = __builtin_amdgcn_mfma_f32_16x16x32_bf16(
              af[fm][kk], bfr[fn][kk], acc[fm][fn], 0, 0, 0);
  }

  // fused epilogue: D = s2[a] + s2[b] - 2G ; hinge/label ; lower-triangle mask
  float local = 0.f;
  const int arow = a0 + wm * 64;
  const int bcol = b0 + wn * 64;
  #pragma unroll
  for (int fm = 0; fm < 4; ++fm) {
    #pragma unroll
    for (int fn = 0; fn < 4; ++fn) {
      #pragma unroll
      for (int rg = 0; rg < 4; ++rg) {
        const int a = arow + fm * 16 + ((lane >> 4) << 2) + rg;  // C/D row
        const int b = bcol + fn * 16 + (lane & 15);              // C/D col
        if (a > b) {
          const float D = s2[a] + s2[b] - 2.0f * acc[fm][fn][rg];
          local += (a - b == 1) ? fmaxf(0.0f, MARG - D) : D;
        }
      }
    }
  }
  #pragma unroll
  for (int o = 32; o; o >>= 1) local += __shfl_down(local, o, 64);
  __shared__ float wp[4];
  if (lane == 0) wp[w] = local;
  __syncthreads();
  if (tid == 0) {
    const double tot = (double)wp[0] + (double)wp[1] + (double)wp[2] + (double)wp[3];
    atomicAdd(acc_out, tot);
  }
}

__global__ void finalize_kernel(const double* __restrict__ acc,
                                float* __restrict__ out) {
  out[0] = (float)(*acc * (1.0 / DENOM));
}

extern "C" void kernel_launch(void* const* d_in, const int* in_sizes, int n_in,
                              void* d_out, int out_size, void* d_ws, size_t ws_size,
                              hipStream_t stream) {
  const float* x = (const float*)d_in[0];
  float* out = (float*)d_out;
  char* ws = (char*)d_ws;
  double* acc          = (double*)ws;                    // 8 B
  float* s2            = (float*)(ws + 1024);            // 16 KB
  unsigned short* Y    = (unsigned short*)(ws + 32768);  // 8 MB bf16 [4096][1024]

  prep_kernel<<<SEQ, 256, 0, stream>>>(x, Y, s2, acc);
  gram_loss_kernel<<<NBLK, 256, 0, stream>>>(Y, s2, acc);
  finalize_kernel<<<1, 1, 0, stream>>>(acc, out);
}

// Round 2
// 74.871 us; speedup vs baseline: 1.3207x; 1.3207x over previous
//
#include <hip/hip_runtime.h>
#include <stdint.h>

#define SEQ   4096
#define MARG  60000.0f
// denom = 4096*4095*1000
#define DENOM 16773120000.0

// ws layout (all slots fully written every call; no init needed):
//   dpart : float[4][4096]    @ 0        (64 KB)  per-batch adjacent-pair partial dists
//   spart : float[1024]       @ 65536    (4 KB)   per-block sum-of-squares partials
//   t2part: double[16]        @ 69632    (128 B)  |t|^2 partials
//   tpart : float[1024][256]  @ 131072   (1 MB)   column-sum partials

__device__ __forceinline__ float dot4(float4 a) {
  return a.x * a.x + a.y * a.y + a.z * a.z + a.w * a.w;
}
__device__ __forceinline__ float dist2(float4 a, float4 b) {
  float dx = a.x - b.x, dy = a.y - b.y, dz = a.z - b.z, dw = a.w - b.w;
  return dx * dx + dy * dy + dz * dz + dw * dw;
}
__device__ __forceinline__ float wred(float v) {
  #pragma unroll
  for (int o = 32; o; o >>= 1) v += __shfl_down(v, o, 64);
  return v;
}
__device__ __forceinline__ double wredd(double v) {
  #pragma unroll
  for (int o = 32; o; o >>= 1) v += __shfl_down(v, o, 64);
  return v;
}

// ---- K1: one streaming pass over x. Block = (n, 16 timesteps); wave = 4 rows.
__global__ __launch_bounds__(256) void pass1_kernel(
    const float* __restrict__ x, float* __restrict__ dpart,
    float* __restrict__ tpart, float* __restrict__ spart) {
  const int b    = blockIdx.x;          // 0..1023
  const int n    = b >> 8;              // batch 0..3
  const int c    = b & 255;             // 16-timestep chunk
  const int tid  = threadIdx.x;
  const int w    = tid >> 6, lane = tid & 63;
  const int s0   = c * 16 + w * 4;      // wave's first timestep
  const float* rowp = x + (((size_t)(n * SEQ + s0)) << 8) + (lane << 2);

  const float4 v0 = *(const float4*)(rowp);
  const float4 v1 = *(const float4*)(rowp + 256);
  const float4 v2 = *(const float4*)(rowp + 512);
  const float4 v3 = *(const float4*)(rowp + 768);
  float4 vp;
  if (s0 > 0) vp = *(const float4*)(rowp - 256);  // boundary row (prev timestep)
  else        vp = v0;                            // dd0 unused for s==0

  float4 tacc;
  tacc.x = v0.x + v1.x + v2.x + v3.x;
  tacc.y = v0.y + v1.y + v2.y + v3.y;
  tacc.z = v0.z + v1.z + v2.z + v3.z;
  tacc.w = v0.w + v1.w + v2.w + v3.w;
  const float s2 = dot4(v0) + dot4(v1) + dot4(v2) + dot4(v3);

  const float r0 = wred(dist2(v0, vp));
  const float r1 = wred(dist2(v1, v0));
  const float r2 = wred(dist2(v2, v1));
  const float r3 = wred(dist2(v3, v2));
  if (lane == 0) {
    float* dp = dpart + n * SEQ + s0;
    if (s0 > 0) dp[0] = r0;   // dpart[n][0] never read
    dp[1] = r1; dp[2] = r2; dp[3] = r3;
  }
  const float s2r = wred(s2);

  __shared__ float4 tl[4][64];
  __shared__ float  sl[4];
  tl[w][lane] = tacc;
  if (lane == 0) sl[w] = s2r;
  __syncthreads();
  if (w == 0) {
    const float4 a = tl[0][lane], bq = tl[1][lane], cq = tl[2][lane], dq = tl[3][lane];
    float4 t;
    t.x = a.x + bq.x + cq.x + dq.x;
    t.y = a.y + bq.y + cq.y + dq.y;
    t.z = a.z + bq.z + cq.z + dq.z;
    t.w = a.w + bq.w + cq.w + dq.w;
    *(float4*)(tpart + b * 256 + (lane << 2)) = t;
    if (lane == 0) spart[b] = sl[0] + sl[1] + sl[2] + sl[3];
  }
}

// ---- K2: tpart [1024][256] -> |t|^2 partials (16 blocks).
__global__ __launch_bounds__(256) void treduce_kernel(
    const float* __restrict__ tpart, double* __restrict__ t2part) {
  const int B = blockIdx.x;             // 0..15
  const int n = B >> 2, fq = B & 3;
  const int tid  = threadIdx.x;
  const int part = tid >> 6, fl = tid & 63;
  const int f = fq * 64 + fl;
  float t = 0.f;
  const int c0 = part * 64;
  #pragma unroll 8
  for (int c = c0; c < c0 + 64; ++c) t += tpart[((n * 256 + c) << 8) + f];
  __shared__ float tl[4][64];
  tl[part][fl] = t;
  __syncthreads();
  if (part == 0) {
    const float tt = tl[0][fl] + tl[1][fl] + tl[2][fl] + tl[3][fl];
    double t2 = (double)tt * (double)tt;
    t2 = wredd(t2);
    if (fl == 0) t2part[B] = t2;
  }
}

// ---- K3: adjacent hinge + final combine.
__global__ __launch_bounds__(256) void finalize_kernel(
    const float* __restrict__ dpart, const float* __restrict__ spart,
    const double* __restrict__ t2part, float* __restrict__ out) {
  const int tid = threadIdx.x;
  double dsum = 0.0, hsum = 0.0, ss = 0.0;
  for (int a = 1 + tid; a < SEQ; a += 256) {
    const float D = dpart[a] + dpart[SEQ + a] + dpart[2 * SEQ + a] + dpart[3 * SEQ + a];
    dsum += (double)D;
    hsum += (double)fmaxf(0.f, MARG - D);
  }
  #pragma unroll
  for (int i = tid; i < 1024; i += 256) ss += (double)spart[i];
  dsum = wredd(dsum); hsum = wredd(hsum); ss = wredd(ss);
  __shared__ double rl[3][4];
  const int w = tid >> 6, lane = tid & 63;
  if (lane == 0) { rl[0][w] = dsum; rl[1][w] = hsum; rl[2][w] = ss; }
  __syncthreads();
  if (tid == 0) {
    const double D  = rl[0][0] + rl[0][1] + rl[0][2] + rl[0][3];
    const double H  = rl[1][0] + rl[1][1] + rl[1][2] + rl[1][3];
    const double S2 = rl[2][0] + rl[2][1] + rl[2][2] + rl[2][3];
    double t2 = 0.0;
    #pragma unroll
    for (int i = 0; i < 16; ++i) t2 += t2part[i];
    // loss_num = Sum_{a>b} D  -  Sum_adj D  +  Sum_adj hinge
    //          = S*Ssum - |t|^2 - dsum + hsum
    const double num = 4096.0 * S2 - t2 - D + H;
    out[0] = (float)(num / DENOM);
  }
}

extern "C" void kernel_launch(void* const* d_in, const int* in_sizes, int n_in,
                              void* d_out, int out_size, void* d_ws, size_t ws_size,
                              hipStream_t stream) {
  const float* x = (const float*)d_in[0];
  float* out = (float*)d_out;
  char* ws = (char*)d_ws;
  float*  dpart  = (float*)(ws);            // 64 KB
  float*  spart  = (float*)(ws + 65536);    // 4 KB
  double* t2part = (double*)(ws + 69632);   // 128 B
  float*  tpart  = (float*)(ws + 131072);   // 1 MB

  pass1_kernel<<<1024, 256, 0, stream>>>(x, dpart, tpart, spart);
  treduce_kernel<<<16, 256, 0, stream>>>(tpart, t2part);
  finalize_kernel<<<1, 256, 0, stream>>>(dpart, spart, t2part, out);
}